// Round 5
// baseline (238.433 us; speedup 1.0000x reference)
//
#include <hip/hip_runtime.h>
#include <math.h>

// Problem constants (B=2, L=2048, H=2048, K=H/NH=128)
#define B_ 2
#define L_ 2048
#define H_ 2048
#define KD_ 128
#define SCALE_ 0.08838834764831845f  // 128^-0.5
#define EPS_ 1e-5f
#define K2_ 4096                     // concat-K for the dual output GEMM

typedef __bf16 bf16x8 __attribute__((ext_vector_type(8)));
typedef float f32x4 __attribute__((ext_vector_type(4)));

static __device__ __forceinline__ float sigmoidf_(float z) {
    return 1.0f / (1.0f + __expf(-z));
}

static __device__ __forceinline__ unsigned short f2bf(float f) {
    unsigned int u = __float_as_uint(f);
    unsigned int r = (u + 0x7fffu + ((u >> 16) & 1u)) >> 16;
    return (unsigned short)r;
}

static __device__ __forceinline__ float bf2f(unsigned short s) {
    return __uint_as_float(((unsigned int)s) << 16);
}

// async global->LDS, 16B per lane; lds base must be wave-uniform
#define ASYNC_COPY16(gsrc, ldst)                                             \
    __builtin_amdgcn_global_load_lds(                                        \
        (const __attribute__((address_space(1))) unsigned int*)(gsrc),       \
        (__attribute__((address_space(3))) unsigned int*)(ldst), 16, 0, 0)

// raw barrier with compiler memory fence (no vmcnt drain, unlike __syncthreads)
#define BAR()                                                                \
    do {                                                                     \
        asm volatile("" ::: "memory");                                       \
        __builtin_amdgcn_s_barrier();                                        \
        asm volatile("" ::: "memory");                                       \
    } while (0)

// ---------------------------------------------------------------------------
// Kernel 0 (merged prep): jobA cast x->bf16 (Abuf x-half) | jobB cast
// [Wq|Wk]->bf16 + zero rrms_acc | jobC cast [Wog|Wig]->bf16 (Bbuf).
// ---------------------------------------------------------------------------
#define JOBA_BLKS 4096   // 1048576 groups of 8
#define JOBB_BLKS 256    // 65536 groups
#define JOBC_BLKS 4096   // 1048576 groups

__global__ __launch_bounds__(256) void prep_all(
    const float* __restrict__ x, const float* __restrict__ Wq,
    const float* __restrict__ Wk, const float* __restrict__ Wog,
    const float* __restrict__ Wig, unsigned short* __restrict__ Abuf,
    unsigned short* __restrict__ Wqk, unsigned short* __restrict__ Bbuf,
    float* __restrict__ rrms_acc)
{
    const int blk = blockIdx.x;
    const float* src;
    unsigned short* dst;
    if (blk < JOBA_BLKS) {
        size_t i = (size_t)blk * 256 + threadIdx.x;
        size_t m = i >> 8, c8 = (i & 255) * 8;
        src = x + m * H_ + c8;
        dst = Abuf + m * K2_ + H_ + c8;
    } else if (blk < JOBA_BLKS + JOBB_BLKS) {
        size_t i = (size_t)(blk - JOBA_BLKS) * 256 + threadIdx.x;
        if (i < 4096) rrms_acc[i] = 0.f;
        const size_t half = (size_t)KD_ * H_ / 8;   // 32768
        src = ((i < half) ? Wq : Wk) + ((i < half) ? i : i - half) * 8;
        dst = Wqk + i * 8;
    } else {
        size_t i = (size_t)(blk - JOBA_BLKS - JOBB_BLKS) * 256 + threadIdx.x;
        const size_t half = (size_t)H_ * H_ / 8;    // 524288
        size_t j = (i < half) ? i : i - half;
        size_t n = j >> 8, c8 = (j & 255) * 8;
        src = ((i < half) ? Wog : Wig) + n * H_ + c8;
        dst = Bbuf + n * K2_ + ((i < half) ? 0 : H_) + c8;
    }
    float4 v0 = *(const float4*)src;
    float4 v1 = *(const float4*)(src + 4);
    ushort4 a, b;
    a.x = f2bf(v0.x); a.y = f2bf(v0.y); a.z = f2bf(v0.z); a.w = f2bf(v0.w);
    b.x = f2bf(v1.x); b.y = f2bf(v1.y); b.z = f2bf(v1.z); b.w = f2bf(v1.w);
    *(ushort4*)dst = a;
    *(ushort4*)(dst + 4) = b;
}

// ---------------------------------------------------------------------------
// Kernel 1: qk projection GEMM — R3-verified one-barrier ring (R4 port).
//   BM=64, BN=256, BK=64; grid = 64 m-tiles x 4 k-slices = 256 blocks.
//   512 thr = 8 waves as 2M x 4N (32x64 per wave, acc[2][4]).
// ---------------------------------------------------------------------------
__global__ __launch_bounds__(512, 2) void qk_proj_mfma(
    const unsigned short* __restrict__ Abuf,
    const unsigned short* __restrict__ Wqk,
    float* __restrict__ partial)
{
    __shared__ alignas(16) unsigned short As[3 * 64 * 64];    // 24 KB
    __shared__ alignas(16) unsigned short Bs[3 * 256 * 64];   // 96 KB
    const int tid  = threadIdx.x;
    const int lane = tid & 63;
    const int w    = tid >> 6;      // 0..7
    const int wrow = w >> 2;        // 0..1  (32-row slice of BM=64)
    const int wcol = w & 3;         // 0..3  (64-col slice of BN=256)
    const int bid  = blockIdx.x;
    const int m0 = (bid >> 2) * 64;    // 64 m-tiles
    const int kz = (bid & 3) * 512;    // 4 K-slices (same partition as before)

    const int frow = lane & 15;
    const int fkb  = (lane >> 4) << 3;       // 0,8,16,24
    const int rxor = (lane & 7) << 3;        // read-side XOR (row&7 == lane&7)

    const int srow = tid >> 3;                              // 0..63
    const int scol = (((tid & 7) ^ (srow & 7)) << 3);
    const unsigned short* agsrc =
        Abuf + (size_t)(m0 + srow) * K2_ + H_ + kz + scol;
    const unsigned short* bgsrc = Wqk + (size_t)srow * H_ + kz + scol;
    unsigned short* As_dst = As + tid * 8;
    unsigned short* Bs_dst = Bs + tid * 8;

// A tile = 64x64 = 4096 elems (1 load/thread); B tile = 256x64 = 16384 (4).
#define QSTAGE_A_(cb, k0)                                                    \
    ASYNC_COPY16(agsrc + (k0), As_dst + (cb) * 4096)
#define QSTAGE_B_(cb, k0, it_)                                               \
    ASYNC_COPY16(bgsrc + (size_t)((it_) * 64) * H_ + (k0),                   \
                 Bs_dst + (cb) * 16384 + (it_) * 4096)
#define QLDA_(buf, i_, ks_)                                                  \
    (*(const bf16x8*)(As + (buf) * 4096 +                                    \
                      (wrow * 32 + (i_) * 16 + frow) * 64 +                  \
                      (((ks_) * 32 + fkb) ^ rxor)))
#define QLDB_(buf, j_, ks_)                                                  \
    (*(const bf16x8*)(Bs + (buf) * 16384 +                                   \
                      (wcol * 64 + (j_) * 16 + frow) * 64 +                  \
                      (((ks_) * 32 + fkb) ^ rxor)))
#define MFMA_(a_, b_, c_)                                                    \
    (c_) = __builtin_amdgcn_mfma_f32_16x16x32_bf16((a_), (b_), (c_), 0, 0, 0)

    f32x4 acc[2][4] = {};

    // ---- prologue: stage tiles 0 and 1 (5 loads each); wait tile 0 ----
    QSTAGE_A_(0, 0);
    QSTAGE_B_(0, 0, 0); QSTAGE_B_(0, 0, 1); QSTAGE_B_(0, 0, 2); QSTAGE_B_(0, 0, 3);
    QSTAGE_A_(1, 64);
    QSTAGE_B_(1, 64, 0); QSTAGE_B_(1, 64, 1); QSTAGE_B_(1, 64, 2); QSTAGE_B_(1, 64, 3);
    asm volatile("s_waitcnt vmcnt(5)" ::: "memory");
    BAR();

    int cur = 0;
    for (int t = 0; t < 8; ++t) {
        int stg = cur + 2; if (stg >= 3) stg -= 3;
        const int kpre = (t + 2) * 64;
        const bool pre = (t + 2 < 8);
        bf16x8 af0[2], bf0[4], af1[2], bf1[4];

        #pragma unroll
        for (int i = 0; i < 2; ++i) af0[i] = QLDA_(cur, i, 0);
        #pragma unroll
        for (int j = 0; j < 4; ++j) bf0[j] = QLDB_(cur, j, 0);
        #pragma unroll
        for (int i = 0; i < 2; ++i) af1[i] = QLDA_(cur, i, 1);
        #pragma unroll
        for (int j = 0; j < 4; ++j) bf1[j] = QLDB_(cur, j, 1);

        if (pre) {
            QSTAGE_A_(stg, kpre);
            QSTAGE_B_(stg, kpre, 0);
            QSTAGE_B_(stg, kpre, 1);
            QSTAGE_B_(stg, kpre, 2);
            QSTAGE_B_(stg, kpre, 3);
        }

        __builtin_amdgcn_s_setprio(1);
        #pragma unroll
        for (int i = 0; i < 2; ++i)
            #pragma unroll
            for (int j = 0; j < 4; ++j)
                MFMA_(af0[i], bf0[j], acc[i][j]);
        #pragma unroll
        for (int i = 0; i < 2; ++i)
            #pragma unroll
            for (int j = 0; j < 4; ++j)
                MFMA_(af1[i], bf1[j], acc[i][j]);
        __builtin_amdgcn_s_setprio(0);

        if (pre) { asm volatile("s_waitcnt vmcnt(5)" ::: "memory"); }
        else     { asm volatile("s_waitcnt vmcnt(0)" ::: "memory"); }
        BAR();

        cur = cur + 1; if (cur == 3) cur = 0;
    }

#undef QSTAGE_A_
#undef QSTAGE_B_
#undef QLDA_
#undef QLDB_
#undef MFMA_

    float* pz = partial + (size_t)(bid & 3) * 4096 * 256;
    #pragma unroll
    for (int i = 0; i < 2; ++i) {
        #pragma unroll
        for (int reg = 0; reg < 4; ++reg) {
            int m = m0 + wrow * 32 + i * 16 + (lane >> 4) * 4 + reg;
            #pragma unroll
            for (int j = 0; j < 4; ++j) {
                int n = wcol * 64 + j * 16 + (lane & 15);
                pz[(size_t)m * 256 + n] = acc[i][j][reg];
            }
        }
    }
}

// ---------------------------------------------------------------------------
// Kernel 2 (fused): split-K reduce + epilogue + chunk-local gate scan +
// chunk-referenced bf16 scaling.
// ---------------------------------------------------------------------------
__global__ __launch_bounds__(256) void scan_scale_kernel(
    const float* __restrict__ partial,
    unsigned short* __restrict__ qt_b, unsigned short* __restrict__ kA_b,
    unsigned short* __restrict__ kB_b)
{
    const int c = blockIdx.x, b = blockIdx.y;
    const int kd = blockIdx.z * 32 + (threadIdx.x & 31);
    const int rg = threadIdx.x >> 5;              // 0..7
    const size_t stride = (size_t)4096 * 256;
    const int row0 = b * L_ + c * 64 + rg * 8;

    float qv[8], kv[8], gp[8];
    float run = 0.f;
    #pragma unroll
    for (int j = 0; j < 8; ++j) {
        size_t off = (size_t)(row0 + j) * 256;
        float sq = partial[off + kd] + partial[stride + off + kd]
                 + partial[2 * stride + off + kd] + partial[3 * stride + off + kd];
        float sk = partial[off + 128 + kd] + partial[stride + off + 128 + kd]
                 + partial[2 * stride + off + 128 + kd]
                 + partial[3 * stride + off + 128 + kd];
        float ksv = sigmoidf_(sk);
        qv[j] = sq * sigmoidf_(sq) * SCALE_;
        kv[j] = ksv;
        run += -log1pf(__expf(ksv));   // g_t in (-1.3133, -0.6931)
        gp[j] = run;
    }
    __shared__ float s_seg[8][32];
    s_seg[rg][threadIdx.x & 31] = run;
    __syncthreads();
    float base = 0.f, total = 0.f;
    #pragma unroll
    for (int r = 0; r < 8; ++r) {
        float v = s_seg[r][threadIdx.x & 31];
        base += (r < rg) ? v : 0.f;
        total += v;
    }
    #pragma unroll
    for (int j = 0; j < 8; ++j) {
        float s = base + gp[j];        // in [-84.05, -0.69]: exp in fp32 range
        size_t idx = (size_t)(row0 + j) * KD_ + kd;
        qt_b[idx] = f2bf(qv[j] * __expf(s));
        kA_b[idx] = f2bf(kv[j] * __expf(-s));
        kB_b[idx] = f2bf(kv[j] * __expf(total - s));
    }
}

// ---------------------------------------------------------------------------
// Kernel 3a: P = qt . k~^T, computed ONCE per (chunk, batch) with causal-band
// mask; written bf16 to Pbuf[cb][64 q][128 keys].
// ---------------------------------------------------------------------------
__global__ __launch_bounds__(256) void p_kernel(
    const unsigned short* __restrict__ qt_b,
    const unsigned short* __restrict__ kA_b,
    const unsigned short* __restrict__ kB_b,
    unsigned short* __restrict__ Pbuf)
{
    const int c = blockIdx.x, b = blockIdx.y;
    const int tid = threadIdx.x;
    const int w = tid >> 6, l = tid & 63;
    const int lr = l & 15, lq = l >> 4;
    const int q0 = c * 64;
    const size_t rowbase = (size_t)b * L_;

    bf16x8 aq[4];
    {
        const unsigned short* qrow = qt_b + (rowbase + q0 + 16 * w + lr) * KD_;
        #pragma unroll
        for (int kt = 0; kt < 4; ++kt)
            aq[kt] = *(const bf16x8*)(qrow + kt * 32 + lq * 8);
    }
    unsigned short* pout = Pbuf + (size_t)(b * 32 + c) * 64 * 128;
    #pragma unroll
    for (int jt = 0; jt < 8; ++jt) {
        f32x4 p = {};
        const int si = jt * 16 + lr;          // window key index 0..127
        const bool prev = (jt < 4);
        const bool dead = (c == 0 && prev);
        if (!dead) {
            int kp = prev ? (q0 - 64 + si) : (q0 + si - 64);
            const unsigned short* kb = (prev ? kB_b : kA_b) + (rowbase + kp) * KD_;
            #pragma unroll
            for (int kt = 0; kt < 4; ++kt) {
                bf16x8 bk = *(const bf16x8*)(kb + kt * 32 + lq * 8);
                p = __builtin_amdgcn_mfma_f32_16x16x32_bf16(aq[kt], bk, p, 0, 0, 0);
            }
        }
        #pragma unroll
        for (int reg = 0; reg < 4; ++reg) {
            int ti = 16 * w + lq * 4 + reg;   // q row 0..63
            bool keep = !dead && (si <= ti + 64);
            pout[ti * 128 + si] = keep ? f2bf(p[reg]) : (unsigned short)0;
        }
    }
}

// ---------------------------------------------------------------------------
// Kernel 3b: O = P @ V. Stages V transposed in LDS; P read from global
// (L2-hot, 1 MB). Writes bf16 o into Abuf o-half + rrms atomics.
// ---------------------------------------------------------------------------
#define SV_ 130   // Vt row stride (elems)

__global__ __launch_bounds__(256) void pv_kernel(
    const unsigned short* __restrict__ Pbuf,
    unsigned short* Abuf,          // reads x-half (cols 2048+), writes o-half
    float* __restrict__ rrms_acc)
{
    const int c  = blockIdx.x;   // chunk 0..31
    const int b  = blockIdx.y;
    const int vt = blockIdx.z;   // 0..15
    const int tid = threadIdx.x;
    const int w = tid >> 6, l = tid & 63;
    const int lr = l & 15, lq = l >> 4;
    const int q0 = c * 64, kpos0 = q0 - 64, v0c = vt * 128;
    const size_t rowbase = (size_t)b * L_;

    __shared__ alignas(16) unsigned short Vt[128 * SV_];

    // ---- stage V transposed: Vt[vcol][key] ----
    {
        const int a = tid & 15;       // col group (8 cols)
        const int kr0 = tid >> 4;
        for (int kr = kr0; kr < 128; kr += 16) {
            int kp = kpos0 + kr;
            ushort4 u0 = {0, 0, 0, 0}, u1 = {0, 0, 0, 0};
            if (kp >= 0) {
                const unsigned short* src =
                    Abuf + (rowbase + kp) * K2_ + H_ + v0c + a * 8;
                u0 = *(const ushort4*)src;
                u1 = *(const ushort4*)(src + 4);
            }
            unsigned short vals[8] = {u0.x, u0.y, u0.z, u0.w,
                                      u1.x, u1.y, u1.z, u1.w};
            #pragma unroll
            for (int j = 0; j < 8; ++j)
                Vt[(a * 8 + j) * SV_ + kr] = vals[j];
        }
    }

    // P fragments from global (independent of the LDS staging)
    bf16x8 ap[4];
    {
        const unsigned short* prow =
            Pbuf + ((size_t)(b * 32 + c) * 64 + 16 * w + lr) * 128;
        #pragma unroll
        for (int kt = 0; kt < 4; ++kt)
            ap[kt] = *(const bf16x8*)(prow + kt * 32 + lq * 8);
    }
    __syncthreads();

    float rsum[4] = {0.f, 0.f, 0.f, 0.f};
    #pragma unroll
    for (int jt = 0; jt < 8; ++jt) {
        f32x4 oa = {};
        const int n = jt * 16 + lr;
        #pragma unroll
        for (int kt = 0; kt < 4; ++kt) {
            const unsigned int* vp =
                (const unsigned int*)(Vt + n * SV_ + kt * 32 + lq * 8);
            union { unsigned int u[4]; bf16x8 v; } bb;
            bb.u[0] = vp[0]; bb.u[1] = vp[1]; bb.u[2] = vp[2]; bb.u[3] = vp[3];
            oa = __builtin_amdgcn_mfma_f32_16x16x32_bf16(ap[kt], bb.v, oa, 0, 0, 0);
        }
        #pragma unroll
        for (int reg = 0; reg < 4; ++reg) {
            int qrow = 16 * w + lq * 4 + reg;
            size_t orow = rowbase + q0 + qrow;
            float val = oa[reg];
            Abuf[orow * K2_ + v0c + n] = f2bf(val);
            rsum[reg] += val * val;
        }
    }
    // reduce sum(o^2) over the 16 lanes sharing lq
    #pragma unroll
    for (int mk = 1; mk < 16; mk <<= 1) {
        #pragma unroll
        for (int reg = 0; reg < 4; ++reg)
            rsum[reg] += __shfl_xor(rsum[reg], mk, 64);
    }
    if (lr == 0) {
        #pragma unroll
        for (int reg = 0; reg < 4; ++reg)
            atomicAdd(&rrms_acc[rowbase + q0 + 16 * w + lq * 4 + reg], rsum[reg]);
    }
}

// ---------------------------------------------------------------------------
// Kernel 4: go = A @ B^T via bf16 MFMA — one-barrier ring (R3 schedule) with
//   FRAGMENT-REUSE wave geometry: BM=128, BN=256, BK=64, 256 blocks (1/CU),
//   but 256 thr = 4 waves, each owning 128 rows x 64 cols (acc[8][4]).
//   Reads/MFMA drops 0.5 -> 0.375: per CU per K-tile, ds_read_b128 volume
//   falls 128 -> 96 (1536 -> 1152 cyc) vs 1241 cyc MFMA -> MFMA is now the
//   pole (R3/R4 measured 37% util because LDS was the pole at 8 waves).
//   1 wave/SIMD (launch_bounds(256,1): VGPR cap 512; ~260 used, no spill).
//   3-deep LDS ring, prefetch distance 2 (~3300 cyc >> 900 cyc HBM latency),
//   counted s_waitcnt vmcnt(12) per iter (12 staging loads/thread/tile).
//   Per-element K accumulation order identical to R3/R4 (same 32-wide
//   chunks, ks0 then ks1, ascending t) => bit-identical results.
// Fused epilogue: rv = rsqrt(mean(o^2)+eps); out = (o*rv*gw)*go*sigmoid(go).
// ---------------------------------------------------------------------------
__global__ __launch_bounds__(256, 1) void out_gemm_mfma(
    const unsigned short* __restrict__ Abuf,
    const unsigned short* __restrict__ Bbuf,
    const float* __restrict__ gw, const float* __restrict__ rrms_acc,
    float* __restrict__ out)
{
    __shared__ alignas(16) unsigned short As[3 * 128 * 64];   // 48 KB
    __shared__ alignas(16) unsigned short Bs[3 * 256 * 64];   // 96 KB
    const int tid  = threadIdx.x;
    const int lane = tid & 63;
    const int w    = tid >> 6;      // 0..3 (64-col slice of BN=256)
    const int bid  = blockIdx.x;
    const int m0 = (bid >> 3) * 128;   // 32 m-tiles
    const int n0 = (bid & 7) * 256;    // 8 n-tiles == 8 XCDs (T1 locality)

    const int frow = lane & 15;
    const int fkb  = (lane >> 4) << 3;       // 0,8,16,24
    const int rxor = (lane & 7) << 3;        // read-side XOR (row&7 == lane&7)

    // staging: thread tid covers row chunk (tid>>3) within a 32-row group,
    // 16B chunk (tid&7). LDS dest linear; source column pre-swizzled (row&7).
    // (32-row groups: (row&7) == (srow&7) since 32 % 8 == 0.)
    const int srow = tid >> 3;                              // 0..31
    const int scol = (((tid & 7) ^ (srow & 7)) << 3);
    const unsigned short* agsrc = Abuf + (size_t)(m0 + srow) * K2_ + scol;
    const unsigned short* bgsrc = Bbuf + (size_t)(n0 + srow) * K2_ + scol;
    unsigned short* As_dst = As + tid * 8;
    unsigned short* Bs_dst = Bs + tid * 8;

// A tile = 128x64 = 8192 elems (4 row-groups of 32); B = 256x64 = 16384 (8).
#define STAGE_A1_(cb, k0, it_)                                               \
    ASYNC_COPY16(agsrc + (size_t)((it_) * 32) * K2_ + (k0),                  \
                 As_dst + (cb) * 8192 + (it_) * 2048)
#define STAGE_B1_(cb, k0, it_)                                               \
    ASYNC_COPY16(bgsrc + (size_t)((it_) * 32) * K2_ + (k0),                  \
                 Bs_dst + (cb) * 16384 + (it_) * 2048)
#define STAGE_ALL_(cb, k0)                                                   \
    {                                                                        \
        _Pragma("unroll")                                                    \
        for (int it_ = 0; it_ < 4; ++it_) STAGE_A1_(cb, k0, it_);            \
        _Pragma("unroll")                                                    \
        for (int it_ = 0; it_ < 8; ++it_) STAGE_B1_(cb, k0, it_);            \
    }
#define LDA_(buf, i_, ks_)                                                   \
    (*(const bf16x8*)(As + (buf) * 8192 +                                    \
                      ((i_) * 16 + frow) * 64 +                              \
                      (((ks_) * 32 + fkb) ^ rxor)))
#define LDB_(buf, j_, ks_)                                                   \
    (*(const bf16x8*)(Bs + (buf) * 16384 +                                   \
                      (w * 64 + (j_) * 16 + frow) * 64 +                     \
                      (((ks_) * 32 + fkb) ^ rxor)))
#define MFMA_(a_, b_, c_)                                                    \
    (c_) = __builtin_amdgcn_mfma_f32_16x16x32_bf16((a_), (b_), (c_), 0, 0, 0)

    f32x4 acc[8][4] = {};

    // ---- prologue: stage tiles 0 and 1 (12 loads each); wait tile 0 ----
    STAGE_ALL_(0, 0);
    STAGE_ALL_(1, 64);
    asm volatile("s_waitcnt vmcnt(12)" ::: "memory");
    BAR();

    int cur = 0;
    for (int t = 0; t < 64; ++t) {
        int stg = cur + 2; if (stg >= 3) stg -= 3;
        const int kpre = (t + 2) * 64;
        const bool pre = (t + 2 < 64);
        bf16x8 af0[8], bf0[4], af1[8], bf1[4];

        // issue all 24 ds_reads of tile `cur` up front (B first so the
        // first MFMA's operands land earliest); compiler interleaves MFMAs
        // with fine-grained lgkmcnt as operands arrive.
        #pragma unroll
        for (int j = 0; j < 4; ++j) bf0[j] = LDB_(cur, j, 0);
        #pragma unroll
        for (int i = 0; i < 8; ++i) af0[i] = LDA_(cur, i, 0);
        #pragma unroll
        for (int j = 0; j < 4; ++j) bf1[j] = LDB_(cur, j, 1);
        #pragma unroll
        for (int i = 0; i < 8; ++i) af1[i] = LDA_(cur, i, 1);

        // issue next-next tile's staging (slot cur+2 == cur-1, safe: its
        // readers all passed the previous barrier).
        if (pre) STAGE_ALL_(stg, kpre);

        __builtin_amdgcn_s_setprio(1);
        #pragma unroll
        for (int i = 0; i < 8; ++i)
            #pragma unroll
            for (int j = 0; j < 4; ++j)
                MFMA_(af0[i], bf0[j], acc[i][j]);
        #pragma unroll
        for (int i = 0; i < 8; ++i)
            #pragma unroll
            for (int j = 0; j < 4; ++j)
                MFMA_(af1[i], bf1[j], acc[i][j]);
        __builtin_amdgcn_s_setprio(0);

        // single sync point per K-tile: tile t+1 resident after this
        // (only this iter's 12 loads may remain outstanding).
        if (pre) { asm volatile("s_waitcnt vmcnt(12)" ::: "memory"); }
        else     { asm volatile("s_waitcnt vmcnt(0)" ::: "memory"); }
        BAR();

        cur = cur + 1; if (cur == 3) cur = 0;
    }

#undef STAGE_A1_
#undef STAGE_B1_
#undef STAGE_ALL_
#undef LDA_
#undef LDB_
#undef MFMA_

    // ---- fused epilogue (unchanged math) ----
    #pragma unroll
    for (int i = 0; i < 8; ++i) {
        #pragma unroll
        for (int reg = 0; reg < 4; ++reg) {
            int m = m0 + i * 16 + (lane >> 4) * 4 + reg;
            float rv = rsqrtf(rrms_acc[m] * (1.0f / H_) + EPS_);
            #pragma unroll
            for (int j = 0; j < 4; ++j) {
                int n = n0 + w * 64 + j * 16 + (lane & 15);
                float go = acc[i][j][reg];
                float ov = bf2f(Abuf[(size_t)m * K2_ + n]);   // bf16 o
                out[(size_t)m * H_ + n] = ov * rv * gw[n] * go * sigmoidf_(go);
            }
        }
    }
}

// ---------------------------------------------------------------------------
extern "C" void kernel_launch(void* const* d_in, const int* in_sizes, int n_in,
                              void* d_out, int out_size, void* d_ws, size_t ws_size,
                              hipStream_t stream) {
    (void)in_sizes; (void)n_in; (void)out_size; (void)ws_size;
    const float* x   = (const float*)d_in[0];
    const float* Wq  = (const float*)d_in[1];
    const float* Wk  = (const float*)d_in[2];
    const float* Wog = (const float*)d_in[3];
    const float* Wig = (const float*)d_in[4];
    const float* gw  = (const float*)d_in[5];
    float* out = (float*)d_out;

    const size_t MK = (size_t)B_ * L_ * KD_;               // 524288
    unsigned short* Abuf = (unsigned short*)d_ws;          // [4096][4096] bf16
    unsigned short* Bbuf = Abuf + (size_t)4096 * K2_;      // [2048][4096] bf16
    unsigned short* qt_b = Bbuf + (size_t)2048 * K2_;      // [4096][128] bf16
    unsigned short* kA_b = qt_b + MK;
    unsigned short* kB_b = kA_b + MK;
    unsigned short* Wqk  = kB_b + MK;                      // [256][2048] bf16
    unsigned short* Pbuf = Wqk + (size_t)256 * H_;         // [64][64][128] bf16
    float* partial  = (float*)(Pbuf + (size_t)64 * 64 * 128);  // [4][4096][256]
    float* rrms_acc = partial + (size_t)4 * 4096 * 256;    // [4096] fp32
    // ws use: 48 MB bf16 GEMM bufs + 3 MB qk + 1 MB W + 1 MB P + 16 MB partial

    prep_all<<<JOBA_BLKS + JOBB_BLKS + JOBC_BLKS, 256, 0, stream>>>(
        x, Wq, Wk, Wog, Wig, Abuf, Wqk, Bbuf, rrms_acc);
    qk_proj_mfma<<<256, 512, 0, stream>>>(Abuf, Wqk, partial);
    scan_scale_kernel<<<dim3(32, B_, 4), 256, 0, stream>>>(partial, qt_b, kA_b, kB_b);
    p_kernel<<<dim3(32, B_), 256, 0, stream>>>(qt_b, kA_b, kB_b, Pbuf);
    pv_kernel<<<dim3(32, B_, 16), 256, 0, stream>>>(Pbuf, Abuf, rrms_acc);
    out_gemm_mfma<<<256, 256, 0, stream>>>(Abuf, Bbuf, gw, rrms_acc, out);
}

// Round 6
// 232.119 us; speedup vs baseline: 1.0272x; 1.0272x over previous
//
#include <hip/hip_runtime.h>
#include <math.h>

// Problem constants (B=2, L=2048, H=2048, K=H/NH=128)
#define B_ 2
#define L_ 2048
#define H_ 2048
#define KD_ 128
#define SCALE_ 0.08838834764831845f  // 128^-0.5
#define EPS_ 1e-5f
#define K2_ 4096                     // concat-K for the dual output GEMM

typedef __bf16 bf16x8 __attribute__((ext_vector_type(8)));
typedef float f32x4 __attribute__((ext_vector_type(4)));

static __device__ __forceinline__ float sigmoidf_(float z) {
    return 1.0f / (1.0f + __expf(-z));
}

static __device__ __forceinline__ unsigned short f2bf(float f) {
    unsigned int u = __float_as_uint(f);
    unsigned int r = (u + 0x7fffu + ((u >> 16) & 1u)) >> 16;
    return (unsigned short)r;
}

static __device__ __forceinline__ float bf2f(unsigned short s) {
    return __uint_as_float(((unsigned int)s) << 16);
}

// async global->LDS, 16B per lane; lds base must be wave-uniform
#define ASYNC_COPY16(gsrc, ldst)                                             \
    __builtin_amdgcn_global_load_lds(                                        \
        (const __attribute__((address_space(1))) unsigned int*)(gsrc),       \
        (__attribute__((address_space(3))) unsigned int*)(ldst), 16, 0, 0)

// raw barrier with compiler memory fence (no vmcnt drain, unlike __syncthreads)
#define BAR()                                                                \
    do {                                                                     \
        asm volatile("" ::: "memory");                                       \
        __builtin_amdgcn_s_barrier();                                        \
        asm volatile("" ::: "memory");                                       \
    } while (0)

// ---------------------------------------------------------------------------
// Kernel 0 (merged prep): jobA cast x->bf16 (Abuf x-half) | jobB cast
// [Wq|Wk]->bf16 + zero rrms_acc | jobC cast [Wog|Wig]->bf16 (Bbuf).
// ---------------------------------------------------------------------------
#define JOBA_BLKS 4096   // 1048576 groups of 8
#define JOBB_BLKS 256    // 65536 groups
#define JOBC_BLKS 4096   // 1048576 groups

__global__ __launch_bounds__(256) void prep_all(
    const float* __restrict__ x, const float* __restrict__ Wq,
    const float* __restrict__ Wk, const float* __restrict__ Wog,
    const float* __restrict__ Wig, unsigned short* __restrict__ Abuf,
    unsigned short* __restrict__ Wqk, unsigned short* __restrict__ Bbuf,
    float* __restrict__ rrms_acc)
{
    const int blk = blockIdx.x;
    const float* src;
    unsigned short* dst;
    if (blk < JOBA_BLKS) {
        size_t i = (size_t)blk * 256 + threadIdx.x;
        size_t m = i >> 8, c8 = (i & 255) * 8;
        src = x + m * H_ + c8;
        dst = Abuf + m * K2_ + H_ + c8;
    } else if (blk < JOBA_BLKS + JOBB_BLKS) {
        size_t i = (size_t)(blk - JOBA_BLKS) * 256 + threadIdx.x;
        if (i < 4096) rrms_acc[i] = 0.f;
        const size_t half = (size_t)KD_ * H_ / 8;   // 32768
        src = ((i < half) ? Wq : Wk) + ((i < half) ? i : i - half) * 8;
        dst = Wqk + i * 8;
    } else {
        size_t i = (size_t)(blk - JOBA_BLKS - JOBB_BLKS) * 256 + threadIdx.x;
        const size_t half = (size_t)H_ * H_ / 8;    // 524288
        size_t j = (i < half) ? i : i - half;
        size_t n = j >> 8, c8 = (j & 255) * 8;
        src = ((i < half) ? Wog : Wig) + n * H_ + c8;
        dst = Bbuf + n * K2_ + ((i < half) ? 0 : H_) + c8;
    }
    float4 v0 = *(const float4*)src;
    float4 v1 = *(const float4*)(src + 4);
    ushort4 a, b;
    a.x = f2bf(v0.x); a.y = f2bf(v0.y); a.z = f2bf(v0.z); a.w = f2bf(v0.w);
    b.x = f2bf(v1.x); b.y = f2bf(v1.y); b.z = f2bf(v1.z); b.w = f2bf(v1.w);
    *(ushort4*)dst = a;
    *(ushort4*)(dst + 4) = b;
}

// ---------------------------------------------------------------------------
// Kernel 1: qk projection GEMM — R3-verified one-barrier ring (R4 port).
//   BM=64, BN=256, BK=64; grid = 64 m-tiles x 4 k-slices = 256 blocks.
//   512 thr = 8 waves as 2M x 4N (32x64 per wave, acc[2][4]).
// ---------------------------------------------------------------------------
__global__ __launch_bounds__(512, 2) void qk_proj_mfma(
    const unsigned short* __restrict__ Abuf,
    const unsigned short* __restrict__ Wqk,
    float* __restrict__ partial)
{
    __shared__ alignas(16) unsigned short As[3 * 64 * 64];    // 24 KB
    __shared__ alignas(16) unsigned short Bs[3 * 256 * 64];   // 96 KB
    const int tid  = threadIdx.x;
    const int lane = tid & 63;
    const int w    = tid >> 6;      // 0..7
    const int wrow = w >> 2;        // 0..1  (32-row slice of BM=64)
    const int wcol = w & 3;         // 0..3  (64-col slice of BN=256)
    const int bid  = blockIdx.x;
    const int m0 = (bid >> 2) * 64;    // 64 m-tiles
    const int kz = (bid & 3) * 512;    // 4 K-slices (same partition as before)

    const int frow = lane & 15;
    const int fkb  = (lane >> 4) << 3;       // 0,8,16,24
    const int rxor = (lane & 7) << 3;        // read-side XOR (row&7 == lane&7)

    const int srow = tid >> 3;                              // 0..63
    const int scol = (((tid & 7) ^ (srow & 7)) << 3);
    const unsigned short* agsrc =
        Abuf + (size_t)(m0 + srow) * K2_ + H_ + kz + scol;
    const unsigned short* bgsrc = Wqk + (size_t)srow * H_ + kz + scol;
    unsigned short* As_dst = As + tid * 8;
    unsigned short* Bs_dst = Bs + tid * 8;

// A tile = 64x64 = 4096 elems (1 load/thread); B tile = 256x64 = 16384 (4).
#define QSTAGE_A_(cb, k0)                                                    \
    ASYNC_COPY16(agsrc + (k0), As_dst + (cb) * 4096)
#define QSTAGE_B_(cb, k0, it_)                                               \
    ASYNC_COPY16(bgsrc + (size_t)((it_) * 64) * H_ + (k0),                   \
                 Bs_dst + (cb) * 16384 + (it_) * 4096)
#define QLDA_(buf, i_, ks_)                                                  \
    (*(const bf16x8*)(As + (buf) * 4096 +                                    \
                      (wrow * 32 + (i_) * 16 + frow) * 64 +                  \
                      (((ks_) * 32 + fkb) ^ rxor)))
#define QLDB_(buf, j_, ks_)                                                  \
    (*(const bf16x8*)(Bs + (buf) * 16384 +                                   \
                      (wcol * 64 + (j_) * 16 + frow) * 64 +                  \
                      (((ks_) * 32 + fkb) ^ rxor)))
#define MFMA_(a_, b_, c_)                                                    \
    (c_) = __builtin_amdgcn_mfma_f32_16x16x32_bf16((a_), (b_), (c_), 0, 0, 0)

    f32x4 acc[2][4] = {};

    // ---- prologue: stage tiles 0 and 1 (5 loads each); wait tile 0 ----
    QSTAGE_A_(0, 0);
    QSTAGE_B_(0, 0, 0); QSTAGE_B_(0, 0, 1); QSTAGE_B_(0, 0, 2); QSTAGE_B_(0, 0, 3);
    QSTAGE_A_(1, 64);
    QSTAGE_B_(1, 64, 0); QSTAGE_B_(1, 64, 1); QSTAGE_B_(1, 64, 2); QSTAGE_B_(1, 64, 3);
    asm volatile("s_waitcnt vmcnt(5)" ::: "memory");
    BAR();

    int cur = 0;
    for (int t = 0; t < 8; ++t) {
        int stg = cur + 2; if (stg >= 3) stg -= 3;
        const int kpre = (t + 2) * 64;
        const bool pre = (t + 2 < 8);
        bf16x8 af0[2], bf0[4], af1[2], bf1[4];

        #pragma unroll
        for (int i = 0; i < 2; ++i) af0[i] = QLDA_(cur, i, 0);
        #pragma unroll
        for (int j = 0; j < 4; ++j) bf0[j] = QLDB_(cur, j, 0);
        #pragma unroll
        for (int i = 0; i < 2; ++i) af1[i] = QLDA_(cur, i, 1);
        #pragma unroll
        for (int j = 0; j < 4; ++j) bf1[j] = QLDB_(cur, j, 1);

        if (pre) {
            QSTAGE_A_(stg, kpre);
            QSTAGE_B_(stg, kpre, 0);
            QSTAGE_B_(stg, kpre, 1);
            QSTAGE_B_(stg, kpre, 2);
            QSTAGE_B_(stg, kpre, 3);
        }

        __builtin_amdgcn_s_setprio(1);
        #pragma unroll
        for (int i = 0; i < 2; ++i)
            #pragma unroll
            for (int j = 0; j < 4; ++j)
                MFMA_(af0[i], bf0[j], acc[i][j]);
        #pragma unroll
        for (int i = 0; i < 2; ++i)
            #pragma unroll
            for (int j = 0; j < 4; ++j)
                MFMA_(af1[i], bf1[j], acc[i][j]);
        __builtin_amdgcn_s_setprio(0);

        if (pre) { asm volatile("s_waitcnt vmcnt(5)" ::: "memory"); }
        else     { asm volatile("s_waitcnt vmcnt(0)" ::: "memory"); }
        BAR();

        cur = cur + 1; if (cur == 3) cur = 0;
    }

#undef QSTAGE_A_
#undef QSTAGE_B_
#undef QLDA_
#undef QLDB_
#undef MFMA_

    float* pz = partial + (size_t)(bid & 3) * 4096 * 256;
    #pragma unroll
    for (int i = 0; i < 2; ++i) {
        #pragma unroll
        for (int reg = 0; reg < 4; ++reg) {
            int m = m0 + wrow * 32 + i * 16 + (lane >> 4) * 4 + reg;
            #pragma unroll
            for (int j = 0; j < 4; ++j) {
                int n = wcol * 64 + j * 16 + (lane & 15);
                pz[(size_t)m * 256 + n] = acc[i][j][reg];
            }
        }
    }
}

// ---------------------------------------------------------------------------
// Kernel 2 (fused): split-K reduce + epilogue + chunk-local gate scan +
// chunk-referenced bf16 scaling.
// ---------------------------------------------------------------------------
__global__ __launch_bounds__(256) void scan_scale_kernel(
    const float* __restrict__ partial,
    unsigned short* __restrict__ qt_b, unsigned short* __restrict__ kA_b,
    unsigned short* __restrict__ kB_b)
{
    const int c = blockIdx.x, b = blockIdx.y;
    const int kd = blockIdx.z * 32 + (threadIdx.x & 31);
    const int rg = threadIdx.x >> 5;              // 0..7
    const size_t stride = (size_t)4096 * 256;
    const int row0 = b * L_ + c * 64 + rg * 8;

    float qv[8], kv[8], gp[8];
    float run = 0.f;
    #pragma unroll
    for (int j = 0; j < 8; ++j) {
        size_t off = (size_t)(row0 + j) * 256;
        float sq = partial[off + kd] + partial[stride + off + kd]
                 + partial[2 * stride + off + kd] + partial[3 * stride + off + kd];
        float sk = partial[off + 128 + kd] + partial[stride + off + 128 + kd]
                 + partial[2 * stride + off + 128 + kd]
                 + partial[3 * stride + off + 128 + kd];
        float ksv = sigmoidf_(sk);
        qv[j] = sq * sigmoidf_(sq) * SCALE_;
        kv[j] = ksv;
        run += -log1pf(__expf(ksv));   // g_t in (-1.3133, -0.6931)
        gp[j] = run;
    }
    __shared__ float s_seg[8][32];
    s_seg[rg][threadIdx.x & 31] = run;
    __syncthreads();
    float base = 0.f, total = 0.f;
    #pragma unroll
    for (int r = 0; r < 8; ++r) {
        float v = s_seg[r][threadIdx.x & 31];
        base += (r < rg) ? v : 0.f;
        total += v;
    }
    #pragma unroll
    for (int j = 0; j < 8; ++j) {
        float s = base + gp[j];        // in [-84.05, -0.69]: exp in fp32 range
        size_t idx = (size_t)(row0 + j) * KD_ + kd;
        qt_b[idx] = f2bf(qv[j] * __expf(s));
        kA_b[idx] = f2bf(kv[j] * __expf(-s));
        kB_b[idx] = f2bf(kv[j] * __expf(total - s));
    }
}

// ---------------------------------------------------------------------------
// Kernel 3 (fused p+pv): per (chunk, batch, vt-pair) block.
//   Phase 1: P = qt . k~^T recomputed in-block (bit-identical MFMA sequence
//   to the old p_kernel: same inputs, same kt order, same causal mask),
//   written bf16 to padded LDS Pl[64][136] (stride 272B: 16B-aligned b128
//   reads, bank rotation 4/row -> 2-way = free).
//   Phase 2: loop over 2 vt tiles {stage V^T, O += P@V} (exact old pv code;
//   ap now read from LDS). rsum accumulated across the pair -> one atomic.
//   Removes: p_kernel launch (64 blocks, 25% fill, pure latency) + Pbuf
//   global round-trip. P-duplication cost: 32 MFMA + 1 LDS transpose per
//   block (x8 vs x1) ~ 0.5us/CU.
// Grid (32, B, 8), 256 threads. LDS 49.5 KB -> 2 blocks/CU (grid-limited).
// ---------------------------------------------------------------------------
#define SV_ 130   // Vt row stride (elems)
#define SP_ 136   // Pl row stride (elems); 136*2=272B = 17 x 16B

__global__ __launch_bounds__(256) void pv_fused(
    const unsigned short* __restrict__ qt_b,
    const unsigned short* __restrict__ kA_b,
    const unsigned short* __restrict__ kB_b,
    unsigned short* Abuf,          // reads x-half (cols 2048+), writes o-half
    float* __restrict__ rrms_acc)
{
    const int c  = blockIdx.x;   // chunk 0..31
    const int b  = blockIdx.y;
    const int vg = blockIdx.z;   // vt pair 0..7
    const int tid = threadIdx.x;
    const int w = tid >> 6, l = tid & 63;
    const int lr = l & 15, lq = l >> 4;
    const int q0 = c * 64, kpos0 = q0 - 64;
    const size_t rowbase = (size_t)b * L_;

    __shared__ alignas(16) unsigned short Pl[64 * SP_];   // 17.0 KB
    __shared__ alignas(16) unsigned short Vt[128 * SV_];  // 32.5 KB

    // ---- phase 1: P into LDS (exact p_kernel math) ----
    {
        bf16x8 aq[4];
        const unsigned short* qrow = qt_b + (rowbase + q0 + 16 * w + lr) * KD_;
        #pragma unroll
        for (int kt = 0; kt < 4; ++kt)
            aq[kt] = *(const bf16x8*)(qrow + kt * 32 + lq * 8);
        #pragma unroll
        for (int jt = 0; jt < 8; ++jt) {
            f32x4 p = {};
            const int si = jt * 16 + lr;          // window key index 0..127
            const bool prev = (jt < 4);
            const bool dead = (c == 0 && prev);
            if (!dead) {
                int kp = prev ? (q0 - 64 + si) : (q0 + si - 64);
                const unsigned short* kb =
                    (prev ? kB_b : kA_b) + (rowbase + kp) * KD_;
                #pragma unroll
                for (int kt = 0; kt < 4; ++kt) {
                    bf16x8 bk = *(const bf16x8*)(kb + kt * 32 + lq * 8);
                    p = __builtin_amdgcn_mfma_f32_16x16x32_bf16(aq[kt], bk, p,
                                                                0, 0, 0);
                }
            }
            #pragma unroll
            for (int reg = 0; reg < 4; ++reg) {
                int ti = 16 * w + lq * 4 + reg;   // q row 0..63
                bool keep = !dead && (si <= ti + 64);
                Pl[ti * SP_ + si] = keep ? f2bf(p[reg]) : (unsigned short)0;
            }
        }
    }
    __syncthreads();

    // P fragments from LDS (row 16w+lr belongs to wave w's own stripe)
    bf16x8 ap[4];
    #pragma unroll
    for (int kt = 0; kt < 4; ++kt)
        ap[kt] = *(const bf16x8*)(Pl + (16 * w + lr) * SP_ + kt * 32 + lq * 8);

    float rsum[4] = {0.f, 0.f, 0.f, 0.f};

    #pragma unroll
    for (int h = 0; h < 2; ++h) {
        const int vt = vg * 2 + h;
        const int v0c = vt * 128;
        if (h) __syncthreads();   // Vt reuse: wait until h=0's reads are done

        // ---- stage V transposed: Vt[vcol][key] (exact old pv code) ----
        {
            const int a = tid & 15;       // col group (8 cols)
            const int kr0 = tid >> 4;
            for (int kr = kr0; kr < 128; kr += 16) {
                int kp = kpos0 + kr;
                ushort4 u0 = {0, 0, 0, 0}, u1 = {0, 0, 0, 0};
                if (kp >= 0) {
                    const unsigned short* src =
                        Abuf + (rowbase + kp) * K2_ + H_ + v0c + a * 8;
                    u0 = *(const ushort4*)src;
                    u1 = *(const ushort4*)(src + 4);
                }
                unsigned short vals[8] = {u0.x, u0.y, u0.z, u0.w,
                                          u1.x, u1.y, u1.z, u1.w};
                #pragma unroll
                for (int j = 0; j < 8; ++j)
                    Vt[(a * 8 + j) * SV_ + kr] = vals[j];
            }
        }
        __syncthreads();

        #pragma unroll
        for (int jt = 0; jt < 8; ++jt) {
            f32x4 oa = {};
            const int n = jt * 16 + lr;
            #pragma unroll
            for (int kt = 0; kt < 4; ++kt) {
                const unsigned int* vp =
                    (const unsigned int*)(Vt + n * SV_ + kt * 32 + lq * 8);
                union { unsigned int u[4]; bf16x8 v; } bb;
                bb.u[0] = vp[0]; bb.u[1] = vp[1];
                bb.u[2] = vp[2]; bb.u[3] = vp[3];
                oa = __builtin_amdgcn_mfma_f32_16x16x32_bf16(ap[kt], bb.v, oa,
                                                             0, 0, 0);
            }
            #pragma unroll
            for (int reg = 0; reg < 4; ++reg) {
                int qrow = 16 * w + lq * 4 + reg;
                size_t orow = rowbase + q0 + qrow;
                float val = oa[reg];
                Abuf[orow * K2_ + v0c + n] = f2bf(val);
                rsum[reg] += val * val;
            }
        }
    }

    // reduce sum(o^2) over the 16 lanes sharing lq; one atomic per pair
    #pragma unroll
    for (int mk = 1; mk < 16; mk <<= 1) {
        #pragma unroll
        for (int reg = 0; reg < 4; ++reg)
            rsum[reg] += __shfl_xor(rsum[reg], mk, 64);
    }
    if (lr == 0) {
        #pragma unroll
        for (int reg = 0; reg < 4; ++reg)
            atomicAdd(&rrms_acc[rowbase + q0 + 16 * w + lq * 4 + reg], rsum[reg]);
    }
}

// ---------------------------------------------------------------------------
// Kernel 4: go = A @ B^T via bf16 MFMA — one-barrier ring schedule (R3,
//   verified 75.4-76.9us / MfmaUtil 37% / VGPR 88 across R3+R4).
//   BM=128, BN=256, BK=64; 1D grid of 256 blocks (1/CU, full fill).
//   512 thr = 8 waves as 2M x 4N (64x64/wave, acc[4][4]). 3-deep LDS ring,
//   prefetch distance 2, one counted s_waitcnt vmcnt(6) + s_barrier per
//   K-tile. (R5's 4-wave/acc[8][4] variant regressed to 88.6us: 1 wave/SIMD
//   has no TLP to hide LDS/DMA latency — reverted.)
// Fused epilogue: rv = rsqrt(mean(o^2)+eps); out = (o*rv*gw)*go*sigmoid(go).
// ---------------------------------------------------------------------------
__global__ __launch_bounds__(512, 2) void out_gemm_mfma(
    const unsigned short* __restrict__ Abuf,
    const unsigned short* __restrict__ Bbuf,
    const float* __restrict__ gw, const float* __restrict__ rrms_acc,
    float* __restrict__ out)
{
    __shared__ alignas(16) unsigned short As[3 * 128 * 64];   // 48 KB
    __shared__ alignas(16) unsigned short Bs[3 * 256 * 64];   // 96 KB
    const int tid  = threadIdx.x;
    const int lane = tid & 63;
    const int w    = tid >> 6;      // 0..7
    const int wrow = w >> 2;        // 0..1  (64-row slice of BM=128)
    const int wcol = w & 3;         // 0..3  (64-col slice of BN=256)
    const int bid  = blockIdx.x;
    const int m0 = (bid >> 3) * 128;   // 32 m-tiles
    const int n0 = (bid & 7) * 256;    // 8 n-tiles == 8 XCDs (T1 locality)

    const int frow = lane & 15;
    const int fkb  = (lane >> 4) << 3;       // 0,8,16,24
    const int rxor = (lane & 7) << 3;        // read-side XOR (row&7 == lane&7)

    const int srow = tid >> 3;                              // 0..63
    const int scol = (((tid & 7) ^ (srow & 7)) << 3);
    const unsigned short* agsrc = Abuf + (size_t)(m0 + srow) * K2_ + scol;
    const unsigned short* bgsrc = Bbuf + (size_t)(n0 + srow) * K2_ + scol;
    unsigned short* As_dst = As + tid * 8;
    unsigned short* Bs_dst = Bs + tid * 8;

// A tile = 128x64 = 8192 elems (2 row-groups); B tile = 256x64 = 16384 (4).
#define STAGE_A2_(cb, k0)                                                    \
    {                                                                        \
        ASYNC_COPY16(agsrc + (k0), As_dst + (cb) * 8192);                    \
        ASYNC_COPY16(agsrc + (size_t)64 * K2_ + (k0),                        \
                     As_dst + (cb) * 8192 + 4096);                           \
    }
#define STAGE_B1_(cb, k0, it_)                                               \
    ASYNC_COPY16(bgsrc + (size_t)((it_) * 64) * K2_ + (k0),                  \
                 Bs_dst + (cb) * 16384 + (it_) * 4096)
#define LDA_(buf, i_, ks_)                                                   \
    (*(const bf16x8*)(As + (buf) * 8192 +                                    \
                      (wrow * 64 + (i_) * 16 + frow) * 64 +                  \
                      (((ks_) * 32 + fkb) ^ rxor)))
#define LDB_(buf, j_, ks_)                                                   \
    (*(const bf16x8*)(Bs + (buf) * 16384 +                                   \
                      (wcol * 64 + (j_) * 16 + frow) * 64 +                  \
                      (((ks_) * 32 + fkb) ^ rxor)))
#define MFMA_(a_, b_, c_)                                                    \
    (c_) = __builtin_amdgcn_mfma_f32_16x16x32_bf16((a_), (b_), (c_), 0, 0, 0)

    f32x4 acc[4][4] = {};

    // ---- prologue: stage tiles 0 and 1 (6 loads each); wait tile 0 ----
    STAGE_A2_(0, 0);
    STAGE_B1_(0, 0, 0); STAGE_B1_(0, 0, 1); STAGE_B1_(0, 0, 2); STAGE_B1_(0, 0, 3);
    STAGE_A2_(1, 64);
    STAGE_B1_(1, 64, 0); STAGE_B1_(1, 64, 1); STAGE_B1_(1, 64, 2); STAGE_B1_(1, 64, 3);
    asm volatile("s_waitcnt vmcnt(6)" ::: "memory");
    BAR();

    int cur = 0;
    for (int t = 0; t < 64; ++t) {
        int stg = cur + 2; if (stg >= 3) stg -= 3;
        const int kpre = (t + 2) * 64;
        const bool pre = (t + 2 < 64);
        bf16x8 af0[4], bf0[4], af1[4], bf1[4];

        // issue all 16 ds_reads of tile `cur` up front; compiler interleaves
        // MFMAs with fine-grained lgkmcnt as operands arrive.
        #pragma unroll
        for (int i = 0; i < 4; ++i) af0[i] = LDA_(cur, i, 0);
        #pragma unroll
        for (int j = 0; j < 4; ++j) bf0[j] = LDB_(cur, j, 0);
        #pragma unroll
        for (int i = 0; i < 4; ++i) af1[i] = LDA_(cur, i, 1);
        #pragma unroll
        for (int j = 0; j < 4; ++j) bf1[j] = LDB_(cur, j, 1);

        // issue next-next tile's staging (slot cur+2 == cur-1, safe: its
        // readers all passed the previous barrier).
        if (pre) {
            STAGE_A2_(stg, kpre);
            STAGE_B1_(stg, kpre, 0);
            STAGE_B1_(stg, kpre, 1);
            STAGE_B1_(stg, kpre, 2);
            STAGE_B1_(stg, kpre, 3);
        }

        __builtin_amdgcn_s_setprio(1);
        #pragma unroll
        for (int i = 0; i < 4; ++i)
            #pragma unroll
            for (int j = 0; j < 4; ++j)
                MFMA_(af0[i], bf0[j], acc[i][j]);
        #pragma unroll
        for (int i = 0; i < 4; ++i)
            #pragma unroll
            for (int j = 0; j < 4; ++j)
                MFMA_(af1[i], bf1[j], acc[i][j]);
        __builtin_amdgcn_s_setprio(0);

        // single sync point per K-tile: tile t+1 resident after this
        // (only this iter's 6 loads may remain outstanding).
        if (pre) { asm volatile("s_waitcnt vmcnt(6)" ::: "memory"); }
        else     { asm volatile("s_waitcnt vmcnt(0)" ::: "memory"); }
        BAR();

        cur = cur + 1; if (cur == 3) cur = 0;
    }

#undef STAGE_A2_
#undef STAGE_B1_
#undef LDA_
#undef LDB_
#undef MFMA_

    // ---- fused epilogue (unchanged math) ----
    #pragma unroll
    for (int i = 0; i < 4; ++i) {
        #pragma unroll
        for (int reg = 0; reg < 4; ++reg) {
            int m = m0 + wrow * 64 + i * 16 + (lane >> 4) * 4 + reg;
            float rv = rsqrtf(rrms_acc[m] * (1.0f / H_) + EPS_);
            #pragma unroll
            for (int j = 0; j < 4; ++j) {
                int n = n0 + wcol * 64 + j * 16 + (lane & 15);
                float go = acc[i][j][reg];
                float ov = bf2f(Abuf[(size_t)m * K2_ + n]);   // bf16 o
                out[(size_t)m * H_ + n] = ov * rv * gw[n] * go * sigmoidf_(go);
            }
        }
    }
}

// ---------------------------------------------------------------------------
extern "C" void kernel_launch(void* const* d_in, const int* in_sizes, int n_in,
                              void* d_out, int out_size, void* d_ws, size_t ws_size,
                              hipStream_t stream) {
    (void)in_sizes; (void)n_in; (void)out_size; (void)ws_size;
    const float* x   = (const float*)d_in[0];
    const float* Wq  = (const float*)d_in[1];
    const float* Wk  = (const float*)d_in[2];
    const float* Wog = (const float*)d_in[3];
    const float* Wig = (const float*)d_in[4];
    const float* gw  = (const float*)d_in[5];
    float* out = (float*)d_out;

    const size_t MK = (size_t)B_ * L_ * KD_;               // 524288
    unsigned short* Abuf = (unsigned short*)d_ws;          // [4096][4096] bf16
    unsigned short* Bbuf = Abuf + (size_t)4096 * K2_;      // [2048][4096] bf16
    unsigned short* qt_b = Bbuf + (size_t)2048 * K2_;      // [4096][128] bf16
    unsigned short* kA_b = qt_b + MK;
    unsigned short* kB_b = kA_b + MK;
    unsigned short* Wqk  = kB_b + MK;                      // [256][2048] bf16
    unsigned short* Pbuf = Wqk + (size_t)256 * H_;         // (layout slot kept; unused)
    float* partial  = (float*)(Pbuf + (size_t)64 * 64 * 128);  // [4][4096][256]
    float* rrms_acc = partial + (size_t)4 * 4096 * 256;    // [4096] fp32
    // ws use: 48 MB bf16 GEMM bufs + 3 MB qk + 1 MB W + 1 MB (unused) + 16 MB partial

    prep_all<<<JOBA_BLKS + JOBB_BLKS + JOBC_BLKS, 256, 0, stream>>>(
        x, Wq, Wk, Wog, Wig, Abuf, Wqk, Bbuf, rrms_acc);
    qk_proj_mfma<<<256, 512, 0, stream>>>(Abuf, Wqk, partial);
    scan_scale_kernel<<<dim3(32, B_, 4), 256, 0, stream>>>(partial, qt_b, kA_b, kB_b);
    pv_fused<<<dim3(32, B_, 8), 256, 0, stream>>>(qt_b, kA_b, kB_b, Abuf, rrms_acc);
    out_gemm_mfma<<<256, 512, 0, stream>>>(Abuf, Bbuf, gw, rrms_acc, out);
}